// Round 19
// baseline (858.385 us; speedup 1.0000x reference)
//
#include <hip/hip_runtime.h>
#include <stdio.h>

#define NBP   8192
#define MTOT  8192
#define CIN   64
#define CO    128

#define EPR(...) do { fprintf(stderr, __VA_ARGS__); fflush(stderr); } while (0)

// ---------------------------------------------------------------------------
// Zero the 1024-float BN-stats region; write output 0 = new_xyz (f32 copy).
// ---------------------------------------------------------------------------
__global__ void __launch_bounds__(256, 1) StackSAModuleMSG_85761906966880_kernel(
    const float* __restrict__ nxyz, float* __restrict__ out, float* __restrict__ stats)
{
    int i = blockIdx.x * 256 + threadIdx.x;
    if (i < 1024) stats[i] = 0.f;
    if (i < MTOT*3) out[i] = nxyz[i];
}

// ---------------------------------------------------------------------------
// Ball query, both scales: one wave per query; f64 d2 (matches np gold).
// ---------------------------------------------------------------------------
__global__ void __launch_bounds__(64, 1) sa_ballq(
    const float* __restrict__ xyz, const float* __restrict__ new_xyz,
    int* __restrict__ idx0, int* __restrict__ idx1,
    int* __restrict__ empty0, int* __restrict__ empty1)
{
    const double r2a = 0.2 * 0.2;
    const double r2b = 0.4 * 0.4;
    int m    = blockIdx.x;
    int lane = threadIdx.x;
    int b    = m >> 11;
    int base = b * NBP;

    double nx = (double)new_xyz[3*m+0];
    double ny = (double)new_xyz[3*m+1];
    double nz = (double)new_xyz[3*m+2];
    double nn = nx*nx + ny*ny + nz*nz;

    int cnt0 = 0, cnt1 = 0;
    int first0 = base, first1 = base;
    unsigned long long lt = (1ull << lane) - 1ull;

    for (int j = 0; j < NBP; j += 64) {
        int gi = base + j + lane;
        double px = (double)xyz[3*gi+0];
        double py = (double)xyz[3*gi+1];
        double pz = (double)xyz[3*gi+2];
        double pp = px*px + py*py + pz*pz;
        double dt = nx*px + ny*py + nz*pz;
        double d2 = nn + pp - 2.0*dt;
        bool in0 = d2 < r2a;
        bool in1 = d2 < r2b;
        unsigned long long m0 = __ballot(in0);
        unsigned long long m1 = __ballot(in1);
        if (in0) {
            int p = cnt0 + __popcll(m0 & lt);
            if (p < 16) idx0[m*16 + p] = gi;
        }
        if (in1) {
            int p = cnt1 + __popcll(m1 & lt);
            if (p < 32) idx1[m*32 + p] = gi;
        }
        if (cnt0 == 0 && m0) first0 = base + j + (__ffsll((long long)m0) - 1);
        if (cnt1 == 0 && m1) first1 = base + j + (__ffsll((long long)m1) - 1);
        cnt0 += __popcll(m0);
        cnt1 += __popcll(m1);
        if (cnt0 >= 16 && cnt1 >= 32) break;
    }
    int c0 = cnt0 < 16 ? cnt0 : 16;
    int c1 = cnt1 < 32 ? cnt1 : 32;
    if (lane >= c0 && lane < 16) idx0[m*16 + lane] = first0;
    if (lane >= c1 && lane < 32) idx1[m*32 + lane] = first1;
    if (lane == 0) { empty0[m] = (cnt0 == 0); empty1[m] = (cnt1 == 0); }
}

// ---------------------------------------------------------------------------
// Pass 1: 32 rows/block (GROUPS groups of 32/GROUPS samples). x1 = G @ W0^T.
// W0 staged in 2 k-chunks (buffer 128x36, stride 36 == 4 mod 32: conflict-
// free like the measured 68). 4 waves; lane owns cols {li,+32,+64,+96},
// lane-half owns 4 rows. LDS ~31 KB -> 5 blocks/CU.
// ---------------------------------------------------------------------------
template<int GROUPS>
__global__ void __launch_bounds__(256, 4) sa_pass1(
    const float* __restrict__ xyz, const float* __restrict__ feat,
    const float* __restrict__ nxyz, const int* __restrict__ idx,
    const int* __restrict__ empty, const float* __restrict__ w0,
    float* __restrict__ x1, float* __restrict__ ssum, float* __restrict__ ssq)
{
    __shared__ float gs[32*68];
    __shared__ float wch[128*36];
    __shared__ float sred[4*128];
    __shared__ float qred[4*128];
    __shared__ int   lidx[32];
    int bx = blockIdx.x, t = threadIdx.x;
    int wv = t >> 6, L = t & 63, hf = L >> 5, li = L & 31;
    int m0 = bx * GROUPS;

    if (t < 32) lidx[t] = idx[bx*32 + t];
    __syncthreads();
    int emp0 = empty[m0];
    int emp1 = (GROUPS == 2) ? empty[m0+1] : emp0;
    for (int e = t; e < 32*68; e += 256) {
        int n = e / 68, c = e - n*68;
        int g = (GROUPS == 2) ? (n >> 4) : 0;
        float v = 0.f;
        if (c < 67 && !(g ? emp1 : emp0)) {
            int gi = lidx[n];
            int mq = m0 + g;
            v = (c < 3) ? (xyz[3*gi+c] - nxyz[3*mq+c])
                        : feat[(long long)gi*CIN + (c-3)];
        }
        gs[e] = v;
    }

    float acc[4][4];
#pragma unroll
    for (int i = 0; i < 4; i++)
        { acc[i][0]=0.f; acc[i][1]=0.f; acc[i][2]=0.f; acc[i][3]=0.f; }
    int c0 = li, c1 = li+32, c2 = li+64, c3 = li+96;
    int r0 = wv*8 + hf*4;

#pragma unroll
    for (int ch = 0; ch < 2; ch++) {
        const int base = ch ? 36 : 0;
        const int W    = ch ? 32 : 36;
        const int NQ   = ch ? 8  : 9;
        __syncthreads();                       // gs ready / prev chunk done
        for (int e = t; e < 128*W; e += 256) {
            int o = e / W, k = e - o*W;
            int col = base + k;
            wch[o*36 + k] = (col < 67) ? w0[o*67 + col] : 0.f;
        }
        __syncthreads();
        for (int q = 0; q < NQ; q++) {
            int k = 4*q;
            float4 w0v = *(const float4*)(wch + c0*36 + k);
            float4 w1v = *(const float4*)(wch + c1*36 + k);
            float4 w2v = *(const float4*)(wch + c2*36 + k);
            float4 w3v = *(const float4*)(wch + c3*36 + k);
            int kg = base + k;
#pragma unroll
            for (int i = 0; i < 4; i++) {
                float4 g = *(const float4*)(gs + (r0+i)*68 + kg);
                acc[i][0]=fmaf(g.x,w0v.x,acc[i][0]); acc[i][0]=fmaf(g.y,w0v.y,acc[i][0]);
                acc[i][0]=fmaf(g.z,w0v.z,acc[i][0]); acc[i][0]=fmaf(g.w,w0v.w,acc[i][0]);
                acc[i][1]=fmaf(g.x,w1v.x,acc[i][1]); acc[i][1]=fmaf(g.y,w1v.y,acc[i][1]);
                acc[i][1]=fmaf(g.z,w1v.z,acc[i][1]); acc[i][1]=fmaf(g.w,w1v.w,acc[i][1]);
                acc[i][2]=fmaf(g.x,w2v.x,acc[i][2]); acc[i][2]=fmaf(g.y,w2v.y,acc[i][2]);
                acc[i][2]=fmaf(g.z,w2v.z,acc[i][2]); acc[i][2]=fmaf(g.w,w2v.w,acc[i][2]);
                acc[i][3]=fmaf(g.x,w3v.x,acc[i][3]); acc[i][3]=fmaf(g.y,w3v.y,acc[i][3]);
                acc[i][3]=fmaf(g.z,w3v.z,acc[i][3]); acc[i][3]=fmaf(g.w,w3v.w,acc[i][3]);
            }
        }
    }

    long long rbase = (long long)(bx*32) * CO;
    float s[4] = {0,0,0,0}, qv[4] = {0,0,0,0};
#pragma unroll
    for (int i = 0; i < 4; i++) {
        long long rb = rbase + (long long)(r0+i)*CO;
        x1[rb+c0]=acc[i][0]; x1[rb+c1]=acc[i][1];
        x1[rb+c2]=acc[i][2]; x1[rb+c3]=acc[i][3];
#pragma unroll
        for (int j = 0; j < 4; j++) {
            s[j] += acc[i][j]; qv[j] = fmaf(acc[i][j], acc[i][j], qv[j]);
        }
    }
#pragma unroll
    for (int j = 0; j < 4; j++) {
        s[j]  += __shfl_xor(s[j],  32);
        qv[j] += __shfl_xor(qv[j], 32);
    }
    if (hf == 0) {
#pragma unroll
        for (int j = 0; j < 4; j++) {
            sred[wv*128 + li + 32*j] = s[j];
            qred[wv*128 + li + 32*j] = qv[j];
        }
    }
    __syncthreads();
    if (t < 128) {
        float ss = 0.f, qq = 0.f;
#pragma unroll
        for (int r = 0; r < 4; r++) { ss += sred[r*128+t]; qq += qred[r*128+t]; }
        atomicAdd(&ssum[t], ss); atomicAdd(&ssq[t], qq);
    }
}

// ---------------------------------------------------------------------------
// Pass 2: 32 rows/block. h = relu(BN1(x1)) -> LDS (16.4 KB); W1 in 4x32-col
// chunks (18.4 KB buffer); x2 in registers only; per-(m,o) max/min + stats2.
// LDS ~39.9 KB -> 4 blocks/CU.
// ---------------------------------------------------------------------------
template<int GROUPS>
__global__ void __launch_bounds__(256, 4) sa_pass2(
    const float* __restrict__ x1, const float* __restrict__ w1,
    const float* __restrict__ g0, const float* __restrict__ b0,
    const float* __restrict__ s1sum, const float* __restrict__ s1sq,
    float* __restrict__ s2sum, float* __restrict__ s2sq,
    float* __restrict__ mxo, float* __restrict__ mno, float invN)
{
    __shared__ float hs[32*128];
    __shared__ float wsc[128*36];
    __shared__ float kv[128], sv[128];
    __shared__ float sred[4*128];
    __shared__ float qred[4*128];
    int bx = blockIdx.x, t = threadIdx.x;
    int wv = t >> 6, L = t & 63, hf = L >> 5, li = L & 31;
    int m0 = bx * GROUPS;

    if (t < 128) {
        float mean = s1sum[t] * invN;
        float var  = s1sq[t] * invN - mean * mean;
        float k    = rsqrtf(var + 1e-5f) * g0[t];
        kv[t] = k;
        sv[t] = b0[t] - mean * k;
    }
    __syncthreads();

    long long rbase = (long long)(bx*32) * CO;
    for (int e = t; e < 32*32; e += 256) {      // float4 units
        int n = e >> 5, c4 = e & 31;
        float4 v  = *(const float4*)(x1 + rbase + (long long)n*CO + 4*c4);
        float4 kk = *(const float4*)(kv + 4*c4);
        float4 ss = *(const float4*)(sv + 4*c4);
        v.x = fmaxf(fmaf(v.x, kk.x, ss.x), 0.f);
        v.y = fmaxf(fmaf(v.y, kk.y, ss.y), 0.f);
        v.z = fmaxf(fmaf(v.z, kk.z, ss.z), 0.f);
        v.w = fmaxf(fmaf(v.w, kk.w, ss.w), 0.f);
        *(float4*)(hs + n*128 + 4*c4) = v;
    }

    float acc[4][4];
#pragma unroll
    for (int i = 0; i < 4; i++)
        { acc[i][0]=0.f; acc[i][1]=0.f; acc[i][2]=0.f; acc[i][3]=0.f; }
    int c0 = li, c1 = li+32, c2 = li+64, c3 = li+96;
    int r0 = wv*8 + hf*4;

    for (int ch = 0; ch < 4; ch++) {
        __syncthreads();                       // hs ready / prev chunk done
        for (int e = t; e < 128*8; e += 256) { // float4 units
            int o = e >> 3, k4 = e & 7;
            *(float4*)(wsc + o*36 + 4*k4) =
                *(const float4*)(w1 + o*CO + ch*32 + 4*k4);
        }
        __syncthreads();
        for (int q = 0; q < 8; q++) {
            int k  = 4*q;
            int kh = ch*32 + k;
            float4 w0v = *(const float4*)(wsc + c0*36 + k);
            float4 w1v = *(const float4*)(wsc + c1*36 + k);
            float4 w2v = *(const float4*)(wsc + c2*36 + k);
            float4 w3v = *(const float4*)(wsc + c3*36 + k);
#pragma unroll
            for (int i = 0; i < 4; i++) {
                float4 h = *(const float4*)(hs + (r0+i)*128 + kh);
                acc[i][0]=fmaf(h.x,w0v.x,acc[i][0]); acc[i][0]=fmaf(h.y,w0v.y,acc[i][0]);
                acc[i][0]=fmaf(h.z,w0v.z,acc[i][0]); acc[i][0]=fmaf(h.w,w0v.w,acc[i][0]);
                acc[i][1]=fmaf(h.x,w1v.x,acc[i][1]); acc[i][1]=fmaf(h.y,w1v.y,acc[i][1]);
                acc[i][1]=fmaf(h.z,w1v.z,acc[i][1]); acc[i][1]=fmaf(h.w,w1v.w,acc[i][1]);
                acc[i][2]=fmaf(h.x,w2v.x,acc[i][2]); acc[i][2]=fmaf(h.y,w2v.y,acc[i][2]);
                acc[i][2]=fmaf(h.z,w2v.z,acc[i][2]); acc[i][2]=fmaf(h.w,w2v.w,acc[i][2]);
                acc[i][3]=fmaf(h.x,w3v.x,acc[i][3]); acc[i][3]=fmaf(h.y,w3v.y,acc[i][3]);
                acc[i][3]=fmaf(h.z,w3v.z,acc[i][3]); acc[i][3]=fmaf(h.w,w3v.w,acc[i][3]);
            }
        }
    }

    float s[4] = {0,0,0,0}, qv[4] = {0,0,0,0};
    float mx[4] = {-3.4e38f,-3.4e38f,-3.4e38f,-3.4e38f};
    float mn[4] = { 3.4e38f, 3.4e38f, 3.4e38f, 3.4e38f};
#pragma unroll
    for (int i = 0; i < 4; i++) {
#pragma unroll
        for (int j = 0; j < 4; j++) {
            float a = acc[i][j];
            s[j] += a; qv[j] = fmaf(a, a, qv[j]);
            mx[j] = fmaxf(mx[j], a); mn[j] = fminf(mn[j], a);
        }
    }
#pragma unroll
    for (int j = 0; j < 4; j++) {
        s[j]  += __shfl_xor(s[j],  32);
        qv[j] += __shfl_xor(qv[j], 32);
        mx[j]  = fmaxf(mx[j], __shfl_xor(mx[j], 32));
        mn[j]  = fminf(mn[j], __shfl_xor(mn[j], 32));
    }
    if (hf == 0) {
#pragma unroll
        for (int j = 0; j < 4; j++) {
            sred[wv*128 + li + 32*j] = s[j];
            qred[wv*128 + li + 32*j] = qv[j];
        }
    }
    __syncthreads();
    if (t < 128) {
        float ss = 0.f, qq = 0.f;
#pragma unroll
        for (int r = 0; r < 4; r++) { ss += sred[r*128+t]; qq += qred[r*128+t]; }
        atomicAdd(&s2sum[t], ss); atomicAdd(&s2sq[t], qq);
    }
    __syncthreads();
    if (hf == 0) {
#pragma unroll
        for (int j = 0; j < 4; j++) {
            sred[wv*128 + li + 32*j] = mx[j];
            qred[wv*128 + li + 32*j] = mn[j];
        }
    }
    __syncthreads();
    if (t < 128) {
        if (GROUPS == 1) {
            float M = fmaxf(fmaxf(sred[t], sred[128+t]),
                            fmaxf(sred[256+t], sred[384+t]));
            float N = fminf(fminf(qred[t], qred[128+t]),
                            fminf(qred[256+t], qred[384+t]));
            mxo[(long long)m0*128 + t] = M;
            mno[(long long)m0*128 + t] = N;
        } else {
            float M0 = fmaxf(sred[t],      sred[128+t]);
            float N0 = fminf(qred[t],      qred[128+t]);
            float M1 = fmaxf(sred[256+t],  sred[384+t]);
            float N1 = fminf(qred[256+t],  qred[384+t]);
            mxo[(long long)m0*128 + t]     = M0;
            mno[(long long)m0*128 + t]     = N0;
            mxo[(long long)(m0+1)*128 + t] = M1;
            mno[(long long)(m0+1)*128 + t] = N1;
        }
    }
}

// ---------------------------------------------------------------------------
// Pass 3 (tiny): out = relu(k2 * (k2>=0 ? max : min) + sh2) per (m, o).
// ---------------------------------------------------------------------------
__global__ void __launch_bounds__(256, 1) sa_pass3(
    const float* __restrict__ mxo, const float* __restrict__ mno,
    const float* __restrict__ g1, const float* __restrict__ b1,
    const float* __restrict__ s2sum, const float* __restrict__ s2sq,
    float* __restrict__ outp, float invN)
{
    int i = blockIdx.x * 256 + threadIdx.x;
    if (i >= MTOT*128) return;
    int m = i >> 7, o = i & 127;
    float mean = s2sum[o] * invN;
    float var  = s2sq[o] * invN - mean * mean;
    float k    = rsqrtf(var + 1e-5f) * g1[o];
    float sh   = b1[o] - mean * k;
    float v    = (k >= 0.f) ? mxo[i] : mno[i];
    float r    = fmaf(v, k, sh);
    outp[(long long)m*256 + o] = r > 0.f ? r : 0.f;
}

// ---------------------------------------------------------------------------
extern "C" void kernel_launch(void* const* d_in, const int* in_sizes, int n_in,
                              void* d_out, int out_size, void* d_ws, size_t ws_size,
                              hipStream_t stream)
{
    const float* xyz  = (const float*)d_in[0];
    const float* feat = (const float*)d_in[1];
    const float* nxyz = (const float*)d_in[2];
    const float* w00 = (const float*)d_in[5];
    const float* g00 = (const float*)d_in[6];
    const float* b00 = (const float*)d_in[7];
    const float* w01 = (const float*)d_in[8];
    const float* g01 = (const float*)d_in[9];
    const float* b01 = (const float*)d_in[10];
    const float* w10 = (const float*)d_in[11];
    const float* g10 = (const float*)d_in[12];
    const float* b10 = (const float*)d_in[13];
    const float* w11 = (const float*)d_in[14];
    const float* g11 = (const float*)d_in[15];
    const float* b11 = (const float*)d_in[16];
    float* out = (float*)d_out;

    // ws: stats | idx0 | idx1 | empty0/1 | x1 (134 MB) | mx/mn per scale
    char*  wsb    = (char*)d_ws;
    float* stats  = (float*)(wsb);
    int*   idx0   = (int*)(wsb + 4096);
    int*   idx1   = (int*)(wsb + 4096 + 524288);
    int*   empty0 = (int*)(wsb + 4096 + 524288 + 1048576);
    int*   empty1 = (int*)(wsb + 4096 + 524288 + 1048576 + 32768);
    float* x      = (float*)(wsb + 4096 + 524288 + 1048576 + 65536);
    float* mx0    = (float*)(wsb + 150000000);
    float* mn0    = (float*)(wsb + 155000000);
    float* mx1    = (float*)(wsb + 160000000);
    float* mn1    = (float*)(wsb + 165000000);

    StackSAModuleMSG_85761906966880_kernel<<<96, 256, 0, stream>>>(nxyz, out, stats);
    sa_ballq<<<MTOT, 64, 0, stream>>>(xyz, nxyz, idx0, idx1, empty0, empty1);

    float* fout = out + MTOT*3;
    const float invN0 = 1.0f / (float)(MTOT*16);
    const float invN1 = 1.0f / (float)(MTOT*32);
    const int P3B = (MTOT*128 + 255) / 256;

    // scale 0 (r=0.2, ns=16): 2 groups/block -> 32 rows
    sa_pass1<2><<<MTOT/2, 256, 0, stream>>>(xyz, feat, nxyz, idx0, empty0, w00,
                                            x, stats + 0, stats + 128);
    sa_pass2<2><<<MTOT/2, 256, 0, stream>>>(x, w01, g00, b00, stats + 0, stats + 128,
                                            stats + 256, stats + 384, mx0, mn0, invN0);
    sa_pass3<<<P3B, 256, 0, stream>>>(mx0, mn0, g01, b01, stats + 256, stats + 384,
                                      fout, invN0);
    // scale 1 (r=0.4, ns=32): 1 group/block -> 32 rows
    sa_pass1<1><<<MTOT, 256, 0, stream>>>(xyz, feat, nxyz, idx1, empty1, w10,
                                          x, stats + 512, stats + 640);
    sa_pass2<1><<<MTOT, 256, 0, stream>>>(x, w11, g10, b10, stats + 512, stats + 640,
                                          stats + 768, stats + 896, mx1, mn1, invN1);
    sa_pass3<<<P3B, 256, 0, stream>>>(mx1, mn1, g11, b11, stats + 768, stats + 896,
                                      fout + 128, invN1);

    hipError_t e = hipGetLastError();
    if (e != hipSuccess) EPR("[KL] enqueue err=%d (%s)\n", (int)e, hipGetErrorString(e));
}

// Round 20
// 840.531 us; speedup vs baseline: 1.0212x; 1.0212x over previous
//
#include <hip/hip_runtime.h>
#include <stdio.h>

#define NBP   8192
#define MTOT  8192
#define CIN   64
#define CO    128

#define EPR(...) do { fprintf(stderr, __VA_ARGS__); fflush(stderr); } while (0)

// ---------------------------------------------------------------------------
// Zero the 1024-float BN-stats region; write output 0 = new_xyz (f32 copy).
// ---------------------------------------------------------------------------
__global__ void __launch_bounds__(256, 1) StackSAModuleMSG_85761906966880_kernel(
    const float* __restrict__ nxyz, float* __restrict__ out, float* __restrict__ stats)
{
    int i = blockIdx.x * 256 + threadIdx.x;
    if (i < 1024) stats[i] = 0.f;
    if (i < MTOT*3) out[i] = nxyz[i];
}

// ---------------------------------------------------------------------------
// Ball query, both scales: one wave per query; f64 d2 (matches np gold).
// ---------------------------------------------------------------------------
__global__ void __launch_bounds__(64, 1) sa_ballq(
    const float* __restrict__ xyz, const float* __restrict__ new_xyz,
    int* __restrict__ idx0, int* __restrict__ idx1,
    int* __restrict__ empty0, int* __restrict__ empty1)
{
    const double r2a = 0.2 * 0.2;
    const double r2b = 0.4 * 0.4;
    int m    = blockIdx.x;
    int lane = threadIdx.x;
    int b    = m >> 11;
    int base = b * NBP;

    double nx = (double)new_xyz[3*m+0];
    double ny = (double)new_xyz[3*m+1];
    double nz = (double)new_xyz[3*m+2];
    double nn = nx*nx + ny*ny + nz*nz;

    int cnt0 = 0, cnt1 = 0;
    int first0 = base, first1 = base;
    unsigned long long lt = (1ull << lane) - 1ull;

    for (int j = 0; j < NBP; j += 64) {
        int gi = base + j + lane;
        double px = (double)xyz[3*gi+0];
        double py = (double)xyz[3*gi+1];
        double pz = (double)xyz[3*gi+2];
        double pp = px*px + py*py + pz*pz;
        double dt = nx*px + ny*py + nz*pz;
        double d2 = nn + pp - 2.0*dt;
        bool in0 = d2 < r2a;
        bool in1 = d2 < r2b;
        unsigned long long m0 = __ballot(in0);
        unsigned long long m1 = __ballot(in1);
        if (in0) {
            int p = cnt0 + __popcll(m0 & lt);
            if (p < 16) idx0[m*16 + p] = gi;
        }
        if (in1) {
            int p = cnt1 + __popcll(m1 & lt);
            if (p < 32) idx1[m*32 + p] = gi;
        }
        if (cnt0 == 0 && m0) first0 = base + j + (__ffsll((long long)m0) - 1);
        if (cnt1 == 0 && m1) first1 = base + j + (__ffsll((long long)m1) - 1);
        cnt0 += __popcll(m0);
        cnt1 += __popcll(m1);
        if (cnt0 >= 16 && cnt1 >= 32) break;
    }
    int c0 = cnt0 < 16 ? cnt0 : 16;
    int c1 = cnt1 < 32 ? cnt1 : 32;
    if (lane >= c0 && lane < 16) idx0[m*16 + lane] = first0;
    if (lane >= c1 && lane < 32) idx1[m*32 + lane] = first1;
    if (lane == 0) { empty0[m] = (cnt0 == 0); empty1[m] = (cnt1 == 0); }
}

// ---------------------------------------------------------------------------
// Pass 1: 32 rows/block. x1 = G @ W0^T + stats1. W0 in 2 k-chunks (128x36,
// stride 36: (9*li)%8 distinct -> conflict-free). gs stride 68 (17 f4,
// dRow*17 % 8 = 4 -> the hf-split h-reads hit different bank groups).
// LDS ~31.4 KB -> 5 blocks/CU.
// ---------------------------------------------------------------------------
template<int GROUPS>
__global__ void __launch_bounds__(256, 5) sa_pass1(
    const float* __restrict__ xyz, const float* __restrict__ feat,
    const float* __restrict__ nxyz, const int* __restrict__ idx,
    const int* __restrict__ empty, const float* __restrict__ w0,
    float* __restrict__ x1, float* __restrict__ ssum, float* __restrict__ ssq)
{
    __shared__ float gs[32*68];
    __shared__ float wch[128*36];
    __shared__ float sred[4*128];
    __shared__ float qred[4*128];
    __shared__ int   lidx[32];
    int bx = blockIdx.x, t = threadIdx.x;
    int wv = t >> 6, L = t & 63, hf = L >> 5, li = L & 31;
    int m0 = bx * GROUPS;

    if (t < 32) lidx[t] = idx[bx*32 + t];
    __syncthreads();
    int emp0 = empty[m0];
    int emp1 = (GROUPS == 2) ? empty[m0+1] : emp0;
    for (int e = t; e < 32*68; e += 256) {
        int n = e / 68, c = e - n*68;
        int g = (GROUPS == 2) ? (n >> 4) : 0;
        float v = 0.f;
        if (c < 67 && !(g ? emp1 : emp0)) {
            int gi = lidx[n];
            int mq = m0 + g;
            v = (c < 3) ? (xyz[3*gi+c] - nxyz[3*mq+c])
                        : feat[(long long)gi*CIN + (c-3)];
        }
        gs[e] = v;
    }

    float acc[4][4];
#pragma unroll
    for (int i = 0; i < 4; i++)
        { acc[i][0]=0.f; acc[i][1]=0.f; acc[i][2]=0.f; acc[i][3]=0.f; }
    int c0 = li, c1 = li+32, c2 = li+64, c3 = li+96;
    int r0 = wv*8 + hf*4;

#pragma unroll
    for (int ch = 0; ch < 2; ch++) {
        const int base = ch ? 36 : 0;
        const int W    = ch ? 32 : 36;
        const int NQ   = ch ? 8  : 9;
        __syncthreads();                       // gs ready / prev chunk done
        for (int e = t; e < 128*W; e += 256) {
            int o = e / W, k = e - o*W;
            int col = base + k;
            wch[o*36 + k] = (col < 67) ? w0[o*67 + col] : 0.f;
        }
        __syncthreads();
        for (int q = 0; q < NQ; q++) {
            int k = 4*q;
            float4 w0v = *(const float4*)(wch + c0*36 + k);
            float4 w1v = *(const float4*)(wch + c1*36 + k);
            float4 w2v = *(const float4*)(wch + c2*36 + k);
            float4 w3v = *(const float4*)(wch + c3*36 + k);
            int kg = base + k;
#pragma unroll
            for (int i = 0; i < 4; i++) {
                float4 g = *(const float4*)(gs + (r0+i)*68 + kg);
                acc[i][0]=fmaf(g.x,w0v.x,acc[i][0]); acc[i][0]=fmaf(g.y,w0v.y,acc[i][0]);
                acc[i][0]=fmaf(g.z,w0v.z,acc[i][0]); acc[i][0]=fmaf(g.w,w0v.w,acc[i][0]);
                acc[i][1]=fmaf(g.x,w1v.x,acc[i][1]); acc[i][1]=fmaf(g.y,w1v.y,acc[i][1]);
                acc[i][1]=fmaf(g.z,w1v.z,acc[i][1]); acc[i][1]=fmaf(g.w,w1v.w,acc[i][1]);
                acc[i][2]=fmaf(g.x,w2v.x,acc[i][2]); acc[i][2]=fmaf(g.y,w2v.y,acc[i][2]);
                acc[i][2]=fmaf(g.z,w2v.z,acc[i][2]); acc[i][2]=fmaf(g.w,w2v.w,acc[i][2]);
                acc[i][3]=fmaf(g.x,w3v.x,acc[i][3]); acc[i][3]=fmaf(g.y,w3v.y,acc[i][3]);
                acc[i][3]=fmaf(g.z,w3v.z,acc[i][3]); acc[i][3]=fmaf(g.w,w3v.w,acc[i][3]);
            }
        }
    }

    long long rbase = (long long)(bx*32) * CO;
    float s[4] = {0,0,0,0}, qv[4] = {0,0,0,0};
#pragma unroll
    for (int i = 0; i < 4; i++) {
        long long rb = rbase + (long long)(r0+i)*CO;
        x1[rb+c0]=acc[i][0]; x1[rb+c1]=acc[i][1];
        x1[rb+c2]=acc[i][2]; x1[rb+c3]=acc[i][3];
#pragma unroll
        for (int j = 0; j < 4; j++) {
            s[j] += acc[i][j]; qv[j] = fmaf(acc[i][j], acc[i][j], qv[j]);
        }
    }
#pragma unroll
    for (int j = 0; j < 4; j++) {
        s[j]  += __shfl_xor(s[j],  32);
        qv[j] += __shfl_xor(qv[j], 32);
    }
    if (hf == 0) {
#pragma unroll
        for (int j = 0; j < 4; j++) {
            sred[wv*128 + li + 32*j] = s[j];
            qred[wv*128 + li + 32*j] = qv[j];
        }
    }
    __syncthreads();
    if (t < 128) {
        float ss = 0.f, qq = 0.f;
#pragma unroll
        for (int r = 0; r < 4; r++) { ss += sred[r*128+t]; qq += qred[r*128+t]; }
        atomicAdd(&ssum[t], ss); atomicAdd(&ssq[t], qq);
    }
}

// ---------------------------------------------------------------------------
// Pass 2: 32 rows/block. h = relu(BN1(x1)) -> LDS with row stride 132
// (33 f4: dRow=4 -> 132%8=4 -> hf-split h-reads in DIFFERENT bank groups,
// fixing R19's 2.6e7 conflicts). W1 in 8 chunks of 16 cols (stride 20:
// (5*li)%8 all-distinct -> conflict-free). LDS ~31.5 KB -> 5 blocks/CU.
// x2 in registers only; emits per-(m,o) max/min + stats2.
// ---------------------------------------------------------------------------
template<int GROUPS>
__global__ void __launch_bounds__(256, 5) sa_pass2(
    const float* __restrict__ x1, const float* __restrict__ w1,
    const float* __restrict__ g0, const float* __restrict__ b0,
    const float* __restrict__ s1sum, const float* __restrict__ s1sq,
    float* __restrict__ s2sum, float* __restrict__ s2sq,
    float* __restrict__ mxo, float* __restrict__ mno, float invN)
{
    __shared__ float hs[32*132];
    __shared__ float wsc[128*20];
    __shared__ float kv[128], sv[128];
    __shared__ float sred[4*128];
    __shared__ float qred[4*128];
    int bx = blockIdx.x, t = threadIdx.x;
    int wv = t >> 6, L = t & 63, hf = L >> 5, li = L & 31;
    int m0 = bx * GROUPS;

    if (t < 128) {
        float mean = s1sum[t] * invN;
        float var  = s1sq[t] * invN - mean * mean;
        float k    = rsqrtf(var + 1e-5f) * g0[t];
        kv[t] = k;
        sv[t] = b0[t] - mean * k;
    }
    __syncthreads();

    long long rbase = (long long)(bx*32) * CO;
    for (int e = t; e < 32*32; e += 256) {      // float4 units
        int n = e >> 5, c4 = e & 31;
        float4 v  = *(const float4*)(x1 + rbase + (long long)n*CO + 4*c4);
        float4 kk = *(const float4*)(kv + 4*c4);
        float4 ss = *(const float4*)(sv + 4*c4);
        v.x = fmaxf(fmaf(v.x, kk.x, ss.x), 0.f);
        v.y = fmaxf(fmaf(v.y, kk.y, ss.y), 0.f);
        v.z = fmaxf(fmaf(v.z, kk.z, ss.z), 0.f);
        v.w = fmaxf(fmaf(v.w, kk.w, ss.w), 0.f);
        *(float4*)(hs + n*132 + 4*c4) = v;
    }

    float acc[4][4];
#pragma unroll
    for (int i = 0; i < 4; i++)
        { acc[i][0]=0.f; acc[i][1]=0.f; acc[i][2]=0.f; acc[i][3]=0.f; }
    int c0 = li, c1 = li+32, c2 = li+64, c3 = li+96;
    int r0 = wv*8 + hf*4;

    for (int ch = 0; ch < 8; ch++) {
        __syncthreads();                       // hs ready / prev chunk done
        for (int e = t; e < 128*4; e += 256) { // float4 units, 16 cols
            int o = e >> 2, k4 = e & 3;
            *(float4*)(wsc + o*20 + 4*k4) =
                *(const float4*)(w1 + o*CO + ch*16 + 4*k4);
        }
        __syncthreads();
        for (int q = 0; q < 4; q++) {
            int k  = 4*q;
            int kh = ch*16 + k;
            float4 w0v = *(const float4*)(wsc + c0*20 + k);
            float4 w1v = *(const float4*)(wsc + c1*20 + k);
            float4 w2v = *(const float4*)(wsc + c2*20 + k);
            float4 w3v = *(const float4*)(wsc + c3*20 + k);
#pragma unroll
            for (int i = 0; i < 4; i++) {
                float4 h = *(const float4*)(hs + (r0+i)*132 + kh);
                acc[i][0]=fmaf(h.x,w0v.x,acc[i][0]); acc[i][0]=fmaf(h.y,w0v.y,acc[i][0]);
                acc[i][0]=fmaf(h.z,w0v.z,acc[i][0]); acc[i][0]=fmaf(h.w,w0v.w,acc[i][0]);
                acc[i][1]=fmaf(h.x,w1v.x,acc[i][1]); acc[i][1]=fmaf(h.y,w1v.y,acc[i][1]);
                acc[i][1]=fmaf(h.z,w1v.z,acc[i][1]); acc[i][1]=fmaf(h.w,w1v.w,acc[i][1]);
                acc[i][2]=fmaf(h.x,w2v.x,acc[i][2]); acc[i][2]=fmaf(h.y,w2v.y,acc[i][2]);
                acc[i][2]=fmaf(h.z,w2v.z,acc[i][2]); acc[i][2]=fmaf(h.w,w2v.w,acc[i][2]);
                acc[i][3]=fmaf(h.x,w3v.x,acc[i][3]); acc[i][3]=fmaf(h.y,w3v.y,acc[i][3]);
                acc[i][3]=fmaf(h.z,w3v.z,acc[i][3]); acc[i][3]=fmaf(h.w,w3v.w,acc[i][3]);
            }
        }
    }

    float s[4] = {0,0,0,0}, qv[4] = {0,0,0,0};
    float mx[4] = {-3.4e38f,-3.4e38f,-3.4e38f,-3.4e38f};
    float mn[4] = { 3.4e38f, 3.4e38f, 3.4e38f, 3.4e38f};
#pragma unroll
    for (int i = 0; i < 4; i++) {
#pragma unroll
        for (int j = 0; j < 4; j++) {
            float a = acc[i][j];
            s[j] += a; qv[j] = fmaf(a, a, qv[j]);
            mx[j] = fmaxf(mx[j], a); mn[j] = fminf(mn[j], a);
        }
    }
#pragma unroll
    for (int j = 0; j < 4; j++) {
        s[j]  += __shfl_xor(s[j],  32);
        qv[j] += __shfl_xor(qv[j], 32);
        mx[j]  = fmaxf(mx[j], __shfl_xor(mx[j], 32));
        mn[j]  = fminf(mn[j], __shfl_xor(mn[j], 32));
    }
    if (hf == 0) {
#pragma unroll
        for (int j = 0; j < 4; j++) {
            sred[wv*128 + li + 32*j] = s[j];
            qred[wv*128 + li + 32*j] = qv[j];
        }
    }
    __syncthreads();
    if (t < 128) {
        float ss = 0.f, qq = 0.f;
#pragma unroll
        for (int r = 0; r < 4; r++) { ss += sred[r*128+t]; qq += qred[r*128+t]; }
        atomicAdd(&s2sum[t], ss); atomicAdd(&s2sq[t], qq);
    }
    __syncthreads();
    if (hf == 0) {
#pragma unroll
        for (int j = 0; j < 4; j++) {
            sred[wv*128 + li + 32*j] = mx[j];
            qred[wv*128 + li + 32*j] = mn[j];
        }
    }
    __syncthreads();
    if (t < 128) {
        if (GROUPS == 1) {
            float M = fmaxf(fmaxf(sred[t], sred[128+t]),
                            fmaxf(sred[256+t], sred[384+t]));
            float N = fminf(fminf(qred[t], qred[128+t]),
                            fminf(qred[256+t], qred[384+t]));
            mxo[(long long)m0*128 + t] = M;
            mno[(long long)m0*128 + t] = N;
        } else {
            float M0 = fmaxf(sred[t],      sred[128+t]);
            float N0 = fminf(qred[t],      qred[128+t]);
            float M1 = fmaxf(sred[256+t],  sred[384+t]);
            float N1 = fminf(qred[256+t],  qred[384+t]);
            mxo[(long long)m0*128 + t]     = M0;
            mno[(long long)m0*128 + t]     = N0;
            mxo[(long long)(m0+1)*128 + t] = M1;
            mno[(long long)(m0+1)*128 + t] = N1;
        }
    }
}

// ---------------------------------------------------------------------------
// Pass 3 (tiny): out = relu(k2 * (k2>=0 ? max : min) + sh2) per (m, o).
// ---------------------------------------------------------------------------
__global__ void __launch_bounds__(256, 1) sa_pass3(
    const float* __restrict__ mxo, const float* __restrict__ mno,
    const float* __restrict__ g1, const float* __restrict__ b1,
    const float* __restrict__ s2sum, const float* __restrict__ s2sq,
    float* __restrict__ outp, float invN)
{
    int i = blockIdx.x * 256 + threadIdx.x;
    if (i >= MTOT*128) return;
    int m = i >> 7, o = i & 127;
    float mean = s2sum[o] * invN;
    float var  = s2sq[o] * invN - mean * mean;
    float k    = rsqrtf(var + 1e-5f) * g1[o];
    float sh   = b1[o] - mean * k;
    float v    = (k >= 0.f) ? mxo[i] : mno[i];
    float r    = fmaf(v, k, sh);
    outp[(long long)m*256 + o] = r > 0.f ? r : 0.f;
}

// ---------------------------------------------------------------------------
extern "C" void kernel_launch(void* const* d_in, const int* in_sizes, int n_in,
                              void* d_out, int out_size, void* d_ws, size_t ws_size,
                              hipStream_t stream)
{
    const float* xyz  = (const float*)d_in[0];
    const float* feat = (const float*)d_in[1];
    const float* nxyz = (const float*)d_in[2];
    const float* w00 = (const float*)d_in[5];
    const float* g00 = (const float*)d_in[6];
    const float* b00 = (const float*)d_in[7];
    const float* w01 = (const float*)d_in[8];
    const float* g01 = (const float*)d_in[9];
    const float* b01 = (const float*)d_in[10];
    const float* w10 = (const float*)d_in[11];
    const float* g10 = (const float*)d_in[12];
    const float* b10 = (const float*)d_in[13];
    const float* w11 = (const float*)d_in[14];
    const float* g11 = (const float*)d_in[15];
    const float* b11 = (const float*)d_in[16];
    float* out = (float*)d_out;

    // ws: stats | idx0 | idx1 | empty0/1 | x1 (134 MB) | mx/mn per scale
    char*  wsb    = (char*)d_ws;
    float* stats  = (float*)(wsb);
    int*   idx0   = (int*)(wsb + 4096);
    int*   idx1   = (int*)(wsb + 4096 + 524288);
    int*   empty0 = (int*)(wsb + 4096 + 524288 + 1048576);
    int*   empty1 = (int*)(wsb + 4096 + 524288 + 1048576 + 32768);
    float* x      = (float*)(wsb + 4096 + 524288 + 1048576 + 65536);
    float* mx0    = (float*)(wsb + 150000000);
    float* mn0    = (float*)(wsb + 155000000);
    float* mx1    = (float*)(wsb + 160000000);
    float* mn1    = (float*)(wsb + 165000000);

    StackSAModuleMSG_85761906966880_kernel<<<96, 256, 0, stream>>>(nxyz, out, stats);
    sa_ballq<<<MTOT, 64, 0, stream>>>(xyz, nxyz, idx0, idx1, empty0, empty1);

    float* fout = out + MTOT*3;
    const float invN0 = 1.0f / (float)(MTOT*16);
    const float invN1 = 1.0f / (float)(MTOT*32);
    const int P3B = (MTOT*128 + 255) / 256;

    // scale 0 (r=0.2, ns=16): 2 groups/block -> 32 rows
    sa_pass1<2><<<MTOT/2, 256, 0, stream>>>(xyz, feat, nxyz, idx0, empty0, w00,
                                            x, stats + 0, stats + 128);
    sa_pass2<2><<<MTOT/2, 256, 0, stream>>>(x, w01, g00, b00, stats + 0, stats + 128,
                                            stats + 256, stats + 384, mx0, mn0, invN0);
    sa_pass3<<<P3B, 256, 0, stream>>>(mx0, mn0, g01, b01, stats + 256, stats + 384,
                                      fout, invN0);
    // scale 1 (r=0.4, ns=32): 1 group/block -> 32 rows
    sa_pass1<1><<<MTOT, 256, 0, stream>>>(xyz, feat, nxyz, idx1, empty1, w10,
                                          x, stats + 512, stats + 640);
    sa_pass2<1><<<MTOT, 256, 0, stream>>>(x, w11, g10, b10, stats + 512, stats + 640,
                                          stats + 768, stats + 896, mx1, mn1, invN1);
    sa_pass3<<<P3B, 256, 0, stream>>>(mx1, mn1, g11, b11, stats + 768, stats + 896,
                                      fout + 128, invN1);

    hipError_t e = hipGetLastError();
    if (e != hipSuccess) EPR("[KL] enqueue err=%d (%s)\n", (int)e, hipGetErrorString(e));
}

// Round 21
// 657.244 us; speedup vs baseline: 1.3060x; 1.2789x over previous
//
#include <hip/hip_runtime.h>
#include <stdio.h>

#define NBP   8192
#define MTOT  8192
#define CIN   64
#define CO    128

#define EPR(...) do { fprintf(stderr, __VA_ARGS__); fflush(stderr); } while (0)

// ---------------------------------------------------------------------------
// Zero the 1024-float BN-stats region; write output 0 = new_xyz (f32 copy).
// ---------------------------------------------------------------------------
__global__ void __launch_bounds__(256, 1) StackSAModuleMSG_85761906966880_kernel(
    const float* __restrict__ nxyz, float* __restrict__ out, float* __restrict__ stats)
{
    int i = blockIdx.x * 256 + threadIdx.x;
    if (i < 1024) stats[i] = 0.f;
    if (i < MTOT*3) out[i] = nxyz[i];
}

// ---------------------------------------------------------------------------
// Ball query, both scales: one wave per query; f64 d2 (matches np gold).
// ---------------------------------------------------------------------------
__global__ void __launch_bounds__(64, 1) sa_ballq(
    const float* __restrict__ xyz, const float* __restrict__ new_xyz,
    int* __restrict__ idx0, int* __restrict__ idx1,
    int* __restrict__ empty0, int* __restrict__ empty1)
{
    const double r2a = 0.2 * 0.2;
    const double r2b = 0.4 * 0.4;
    int m    = blockIdx.x;
    int lane = threadIdx.x;
    int b    = m >> 11;
    int base = b * NBP;

    double nx = (double)new_xyz[3*m+0];
    double ny = (double)new_xyz[3*m+1];
    double nz = (double)new_xyz[3*m+2];
    double nn = nx*nx + ny*ny + nz*nz;

    int cnt0 = 0, cnt1 = 0;
    int first0 = base, first1 = base;
    unsigned long long lt = (1ull << lane) - 1ull;

    for (int j = 0; j < NBP; j += 64) {
        int gi = base + j + lane;
        double px = (double)xyz[3*gi+0];
        double py = (double)xyz[3*gi+1];
        double pz = (double)xyz[3*gi+2];
        double pp = px*px + py*py + pz*pz;
        double dt = nx*px + ny*py + nz*pz;
        double d2 = nn + pp - 2.0*dt;
        bool in0 = d2 < r2a;
        bool in1 = d2 < r2b;
        unsigned long long m0 = __ballot(in0);
        unsigned long long m1 = __ballot(in1);
        if (in0) {
            int p = cnt0 + __popcll(m0 & lt);
            if (p < 16) idx0[m*16 + p] = gi;
        }
        if (in1) {
            int p = cnt1 + __popcll(m1 & lt);
            if (p < 32) idx1[m*32 + p] = gi;
        }
        if (cnt0 == 0 && m0) first0 = base + j + (__ffsll((long long)m0) - 1);
        if (cnt1 == 0 && m1) first1 = base + j + (__ffsll((long long)m1) - 1);
        cnt0 += __popcll(m0);
        cnt1 += __popcll(m1);
        if (cnt0 >= 16 && cnt1 >= 32) break;
    }
    int c0 = cnt0 < 16 ? cnt0 : 16;
    int c1 = cnt1 < 32 ? cnt1 : 32;
    if (lane >= c0 && lane < 16) idx0[m*16 + lane] = first0;
    if (lane >= c1 && lane < 32) idx1[m*32 + lane] = first1;
    if (lane == 0) { empty0[m] = (cnt0 == 0); empty1[m] = (cnt1 == 0); }
}

// ---------------------------------------------------------------------------
// Pass 1: R18 geometry (measured 0 conflicts): MB=2 groups (ROWS=2*NS),
// 4 waves, lane owns cols {li,+32,+64,+96}, lane-half owns RH=NS/4 rows,
// gs/ws stride 68. NEW: permuted k-layout (feat 0..63 | dxyz 64..66 | pad)
// so feat stages as coalesced float4 and W0 as linear float4 + scatter.
// Same permutation applied to both operands => identical dot (reordered sum).
// ---------------------------------------------------------------------------
template<int NS>
__global__ void __launch_bounds__(256, 2) sa_pass1(
    const float* __restrict__ xyz, const float* __restrict__ feat,
    const float* __restrict__ nxyz, const int* __restrict__ idx,
    const int* __restrict__ empty, const float* __restrict__ w0,
    float* __restrict__ x1, float* __restrict__ ssum, float* __restrict__ ssq)
{
    const int ROWS = 2*NS;
    const int RH   = NS/4;
    __shared__ float gs[ROWS*68];
    __shared__ float ws[128*68];
    __shared__ float sred[8*128];
    __shared__ float qred[8*128];
    __shared__ int   lidx[64];
    int bx = blockIdx.x, t = threadIdx.x;
    int m0 = 2*bx;
    int wv = t >> 6, L = t & 63, hf = L >> 5, li = L & 31;

    if (t < ROWS) lidx[t] = idx[(long long)m0*NS + t];
    __syncthreads();
    int emp0 = empty[m0], emp1 = empty[m0+1];

    // feat -> gs cols 0..63 (coalesced float4 gather)
    for (int e = t; e < ROWS*16; e += 256) {
        int n = e >> 4, c4 = e & 15;
        int gi = lidx[n];
        float4 v = *(const float4*)(feat + (long long)gi*CIN + 4*c4);
        int g = n / NS;
        if (g ? emp1 : emp0) { v.x = 0.f; v.y = 0.f; v.z = 0.f; v.w = 0.f; }
        *(float4*)(gs + n*68 + 4*c4) = v;
    }
    // dxyz -> gs cols 64..66, pad 67 = 0
    for (int e = t; e < ROWS*4; e += 256) {
        int n = e >> 2, c = e & 3;
        float v = 0.f;
        if (c < 3) {
            int g = n / NS;
            if (!(g ? emp1 : emp0)) {
                int gi = lidx[n];
                v = xyz[3*gi+c] - nxyz[3*(m0+g)+c];
            }
        }
        gs[n*68 + 64 + c] = v;
    }
    // W0 (128x67 = 2144 float4) -> ws, permuted: kd = c>=3 ? c-3 : 64+c
    for (int e = t; e < 2144; e += 256) {
        float4 v = *(const float4*)(w0 + 4*e);
        float vv[4] = {v.x, v.y, v.z, v.w};
#pragma unroll
        for (int u = 0; u < 4; u++) {
            int f = 4*e + u;
            int o = f / 67, c = f - o*67;
            int kd = (c >= 3) ? (c - 3) : (64 + c);
            ws[o*68 + kd] = vv[u];
        }
    }
    if (t < 128) ws[t*68 + 67] = 0.f;
    __syncthreads();

    float acc[RH][4];
#pragma unroll
    for (int i = 0; i < RH; i++)
        { acc[i][0]=0.f; acc[i][1]=0.f; acc[i][2]=0.f; acc[i][3]=0.f; }
    int c0 = li, c1 = li+32, c2 = li+64, c3 = li+96;
    int r0 = wv*(NS/2) + hf*RH;

    for (int q = 0; q < 17; q++) {
        int k = 4*q;
        float4 w0v = *(const float4*)(ws + c0*68 + k);
        float4 w1v = *(const float4*)(ws + c1*68 + k);
        float4 w2v = *(const float4*)(ws + c2*68 + k);
        float4 w3v = *(const float4*)(ws + c3*68 + k);
#pragma unroll
        for (int i = 0; i < RH; i++) {
            float4 g = *(const float4*)(gs + (r0+i)*68 + k);
            acc[i][0]=fmaf(g.x,w0v.x,acc[i][0]); acc[i][0]=fmaf(g.y,w0v.y,acc[i][0]);
            acc[i][0]=fmaf(g.z,w0v.z,acc[i][0]); acc[i][0]=fmaf(g.w,w0v.w,acc[i][0]);
            acc[i][1]=fmaf(g.x,w1v.x,acc[i][1]); acc[i][1]=fmaf(g.y,w1v.y,acc[i][1]);
            acc[i][1]=fmaf(g.z,w1v.z,acc[i][1]); acc[i][1]=fmaf(g.w,w1v.w,acc[i][1]);
            acc[i][2]=fmaf(g.x,w2v.x,acc[i][2]); acc[i][2]=fmaf(g.y,w2v.y,acc[i][2]);
            acc[i][2]=fmaf(g.z,w2v.z,acc[i][2]); acc[i][2]=fmaf(g.w,w2v.w,acc[i][2]);
            acc[i][3]=fmaf(g.x,w3v.x,acc[i][3]); acc[i][3]=fmaf(g.y,w3v.y,acc[i][3]);
            acc[i][3]=fmaf(g.z,w3v.z,acc[i][3]); acc[i][3]=fmaf(g.w,w3v.w,acc[i][3]);
        }
    }

    long long gbase = (long long)m0*NS*CO;
    float s[4] = {0,0,0,0}, qv[4] = {0,0,0,0};
#pragma unroll
    for (int i = 0; i < RH; i++) {
        long long rb = gbase + (long long)(r0+i)*CO;
        x1[rb+c0]=acc[i][0]; x1[rb+c1]=acc[i][1];
        x1[rb+c2]=acc[i][2]; x1[rb+c3]=acc[i][3];
#pragma unroll
        for (int j = 0; j < 4; j++) {
            s[j] += acc[i][j]; qv[j] = fmaf(acc[i][j], acc[i][j], qv[j]);
        }
    }
    int p = wv*2 + hf;
    sred[p*128+c0]=s[0]; sred[p*128+c1]=s[1]; sred[p*128+c2]=s[2]; sred[p*128+c3]=s[3];
    qred[p*128+c0]=qv[0]; qred[p*128+c1]=qv[1]; qred[p*128+c2]=qv[2]; qred[p*128+c3]=qv[3];
    __syncthreads();
    if (t < 128) {
        float ss = 0.f, qq = 0.f;
#pragma unroll
        for (int r = 0; r < 8; r++) { ss += sred[r*128+t]; qq += qred[r*128+t]; }
        atomicAdd(&ssum[t], ss); atomicAdd(&ssq[t], qq);
    }
}

// ---------------------------------------------------------------------------
// Pass 2: R18 geometry verbatim (measured 0 conflicts): hs stride 128,
// W1 in two 64-col chunks in a stride-68 panel, 4 waves, Δrow=8 half split.
// x2 in registers; emits per-(m,o) max/min + stats2.
// ---------------------------------------------------------------------------
template<int NS>
__global__ void __launch_bounds__(256, 2) sa_pass2(
    const float* __restrict__ x1, const float* __restrict__ w1,
    const float* __restrict__ g0, const float* __restrict__ b0,
    const float* __restrict__ s1sum, const float* __restrict__ s1sq,
    float* __restrict__ s2sum, float* __restrict__ s2sq,
    float* __restrict__ mxo, float* __restrict__ mno, float invN)
{
    const int ROWS = 2*NS;
    const int RH   = NS/4;
    __shared__ float hs[ROWS*128];
    __shared__ float wsc[128*68];
    __shared__ float kv[128], sv[128];
    __shared__ float sred[8*128];
    __shared__ float qred[8*128];
    int bx = blockIdx.x, t = threadIdx.x;
    int m0 = 2*bx;
    int wv = t >> 6, L = t & 63, hf = L >> 5, li = L & 31;

    if (t < 128) {
        float mean = s1sum[t] * invN;
        float var  = s1sq[t] * invN - mean * mean;
        float k    = rsqrtf(var + 1e-5f) * g0[t];
        kv[t] = k;
        sv[t] = b0[t] - mean * k;
    }
    __syncthreads();

    long long gbase = (long long)m0*NS*CO;
    for (int e = t; e < ROWS*32; e += 256) {    // float4 units
        int n = e >> 5, c4 = e & 31;
        float4 v  = *(const float4*)(x1 + gbase + (long long)n*CO + 4*c4);
        float4 kk = *(const float4*)(kv + 4*c4);
        float4 ss = *(const float4*)(sv + 4*c4);
        v.x = fmaxf(fmaf(v.x, kk.x, ss.x), 0.f);
        v.y = fmaxf(fmaf(v.y, kk.y, ss.y), 0.f);
        v.z = fmaxf(fmaf(v.z, kk.z, ss.z), 0.f);
        v.w = fmaxf(fmaf(v.w, kk.w, ss.w), 0.f);
        *(float4*)(hs + n*128 + 4*c4) = v;
    }

    float acc[RH][4];
#pragma unroll
    for (int i = 0; i < RH; i++)
        { acc[i][0]=0.f; acc[i][1]=0.f; acc[i][2]=0.f; acc[i][3]=0.f; }
    int c0 = li, c1 = li+32, c2 = li+64, c3 = li+96;
    int r0 = wv*(NS/2) + hf*RH;

    for (int ch = 0; ch < 2; ch++) {
        __syncthreads();   // hs ready (ch0) / previous wsc consumed (ch1)
        for (int e = t; e < 128*16; e += 256) { // float4 units
            int o = e >> 4, k4 = e & 15;
            *(float4*)(wsc + o*68 + 4*k4) =
                *(const float4*)(w1 + o*CO + ch*64 + 4*k4);
        }
        __syncthreads();
        for (int q = 0; q < 16; q++) {
            int k  = 4*q;
            int kh = ch*64 + k;
            float4 w0v = *(const float4*)(wsc + c0*68 + k);
            float4 w1v = *(const float4*)(wsc + c1*68 + k);
            float4 w2v = *(const float4*)(wsc + c2*68 + k);
            float4 w3v = *(const float4*)(wsc + c3*68 + k);
#pragma unroll
            for (int i = 0; i < RH; i++) {
                float4 h = *(const float4*)(hs + (r0+i)*128 + kh);
                acc[i][0]=fmaf(h.x,w0v.x,acc[i][0]); acc[i][0]=fmaf(h.y,w0v.y,acc[i][0]);
                acc[i][0]=fmaf(h.z,w0v.z,acc[i][0]); acc[i][0]=fmaf(h.w,w0v.w,acc[i][0]);
                acc[i][1]=fmaf(h.x,w1v.x,acc[i][1]); acc[i][1]=fmaf(h.y,w1v.y,acc[i][1]);
                acc[i][1]=fmaf(h.z,w1v.z,acc[i][1]); acc[i][1]=fmaf(h.w,w1v.w,acc[i][1]);
                acc[i][2]=fmaf(h.x,w2v.x,acc[i][2]); acc[i][2]=fmaf(h.y,w2v.y,acc[i][2]);
                acc[i][2]=fmaf(h.z,w2v.z,acc[i][2]); acc[i][2]=fmaf(h.w,w2v.w,acc[i][2]);
                acc[i][3]=fmaf(h.x,w3v.x,acc[i][3]); acc[i][3]=fmaf(h.y,w3v.y,acc[i][3]);
                acc[i][3]=fmaf(h.z,w3v.z,acc[i][3]); acc[i][3]=fmaf(h.w,w3v.w,acc[i][3]);
            }
        }
    }

    float s[4] = {0,0,0,0}, qv[4] = {0,0,0,0};
    float mx[4] = {-3.4e38f,-3.4e38f,-3.4e38f,-3.4e38f};
    float mn[4] = { 3.4e38f, 3.4e38f, 3.4e38f, 3.4e38f};
#pragma unroll
    for (int i = 0; i < RH; i++) {
#pragma unroll
        for (int j = 0; j < 4; j++) {
            float a = acc[i][j];
            s[j] += a; qv[j] = fmaf(a, a, qv[j]);
            mx[j] = fmaxf(mx[j], a); mn[j] = fminf(mn[j], a);
        }
    }
    int p = wv*2 + hf;
    sred[p*128+c0]=s[0]; sred[p*128+c1]=s[1]; sred[p*128+c2]=s[2]; sred[p*128+c3]=s[3];
    qred[p*128+c0]=qv[0]; qred[p*128+c1]=qv[1]; qred[p*128+c2]=qv[2]; qred[p*128+c3]=qv[3];
    __syncthreads();
    if (t < 128) {
        float ss = 0.f, qq = 0.f;
#pragma unroll
        for (int r = 0; r < 8; r++) { ss += sred[r*128+t]; qq += qred[r*128+t]; }
        atomicAdd(&s2sum[t], ss); atomicAdd(&s2sq[t], qq);
    }
    __syncthreads();
    sred[p*128+c0]=mx[0]; sred[p*128+c1]=mx[1]; sred[p*128+c2]=mx[2]; sred[p*128+c3]=mx[3];
    qred[p*128+c0]=mn[0]; qred[p*128+c1]=mn[1]; qred[p*128+c2]=mn[2]; qred[p*128+c3]=mn[3];
    __syncthreads();
    if (t < 128) {
        float M0 = -3.4e38f, N0 = 3.4e38f, M1 = -3.4e38f, N1 = 3.4e38f;
#pragma unroll
        for (int r = 0; r < 4; r++) {               // partials p=0..3 -> m0
            M0 = fmaxf(M0, sred[r*128+t]); N0 = fminf(N0, qred[r*128+t]);
        }
#pragma unroll
        for (int r = 4; r < 8; r++) {               // partials p=4..7 -> m0+1
            M1 = fmaxf(M1, sred[r*128+t]); N1 = fminf(N1, qred[r*128+t]);
        }
        mxo[(long long)m0*128 + t]     = M0; mno[(long long)m0*128 + t]     = N0;
        mxo[(long long)(m0+1)*128 + t] = M1; mno[(long long)(m0+1)*128 + t] = N1;
    }
}

// ---------------------------------------------------------------------------
// Pass 3 (tiny): out = relu(k2 * (k2>=0 ? max : min) + sh2) per (m, o).
// ---------------------------------------------------------------------------
__global__ void __launch_bounds__(256, 1) sa_pass3(
    const float* __restrict__ mxo, const float* __restrict__ mno,
    const float* __restrict__ g1, const float* __restrict__ b1,
    const float* __restrict__ s2sum, const float* __restrict__ s2sq,
    float* __restrict__ outp, float invN)
{
    int i = blockIdx.x * 256 + threadIdx.x;
    if (i >= MTOT*128) return;
    int m = i >> 7, o = i & 127;
    float mean = s2sum[o] * invN;
    float var  = s2sq[o] * invN - mean * mean;
    float k    = rsqrtf(var + 1e-5f) * g1[o];
    float sh   = b1[o] - mean * k;
    float v    = (k >= 0.f) ? mxo[i] : mno[i];
    float r    = fmaf(v, k, sh);
    outp[(long long)m*256 + o] = r > 0.f ? r : 0.f;
}

// ---------------------------------------------------------------------------
extern "C" void kernel_launch(void* const* d_in, const int* in_sizes, int n_in,
                              void* d_out, int out_size, void* d_ws, size_t ws_size,
                              hipStream_t stream)
{
    const float* xyz  = (const float*)d_in[0];
    const float* feat = (const float*)d_in[1];
    const float* nxyz = (const float*)d_in[2];
    const float* w00 = (const float*)d_in[5];
    const float* g00 = (const float*)d_in[6];
    const float* b00 = (const float*)d_in[7];
    const float* w01 = (const float*)d_in[8];
    const float* g01 = (const float*)d_in[9];
    const float* b01 = (const float*)d_in[10];
    const float* w10 = (const float*)d_in[11];
    const float* g10 = (const float*)d_in[12];
    const float* b10 = (const float*)d_in[13];
    const float* w11 = (const float*)d_in[14];
    const float* g11 = (const float*)d_in[15];
    const float* b11 = (const float*)d_in[16];
    float* out = (float*)d_out;

    // ws: stats | idx0 | idx1 | empty0/1 | x1 (134 MB) | mx/mn per scale
    char*  wsb    = (char*)d_ws;
    float* stats  = (float*)(wsb);
    int*   idx0   = (int*)(wsb + 4096);
    int*   idx1   = (int*)(wsb + 4096 + 524288);
    int*   empty0 = (int*)(wsb + 4096 + 524288 + 1048576);
    int*   empty1 = (int*)(wsb + 4096 + 524288 + 1048576 + 32768);
    float* x      = (float*)(wsb + 4096 + 524288 + 1048576 + 65536);
    float* mx0    = (float*)(wsb + 150000000);
    float* mn0    = (float*)(wsb + 155000000);
    float* mx1    = (float*)(wsb + 160000000);
    float* mn1    = (float*)(wsb + 165000000);

    StackSAModuleMSG_85761906966880_kernel<<<96, 256, 0, stream>>>(nxyz, out, stats);
    sa_ballq<<<MTOT, 64, 0, stream>>>(xyz, nxyz, idx0, idx1, empty0, empty1);

    float* fout = out + MTOT*3;
    const float invN0 = 1.0f / (float)(MTOT*16);
    const float invN1 = 1.0f / (float)(MTOT*32);
    const int P3B = (MTOT*128 + 255) / 256;
    const int GB  = MTOT/2;   // 2 query groups per block

    // scale 0 (r=0.2, ns=16)
    sa_pass1<16><<<GB, 256, 0, stream>>>(xyz, feat, nxyz, idx0, empty0, w00,
                                         x, stats + 0, stats + 128);
    sa_pass2<16><<<GB, 256, 0, stream>>>(x, w01, g00, b00, stats + 0, stats + 128,
                                         stats + 256, stats + 384, mx0, mn0, invN0);
    sa_pass3<<<P3B, 256, 0, stream>>>(mx0, mn0, g01, b01, stats + 256, stats + 384,
                                      fout, invN0);
    // scale 1 (r=0.4, ns=32)
    sa_pass1<32><<<GB, 256, 0, stream>>>(xyz, feat, nxyz, idx1, empty1, w10,
                                         x, stats + 512, stats + 640);
    sa_pass2<32><<<GB, 256, 0, stream>>>(x, w11, g10, b10, stats + 512, stats + 640,
                                         stats + 768, stats + 896, mx1, mn1, invN1);
    sa_pass3<<<P3B, 256, 0, stream>>>(mx1, mn1, g11, b11, stats + 768, stats + 896,
                                      fout + 128, invN1);

    hipError_t e = hipGetLastError();
    if (e != hipSuccess) EPR("[KL] enqueue err=%d (%s)\n", (int)e, hipGetErrorString(e));
}